// Round 5
// baseline (285.514 us; speedup 1.0000x reference)
//
#include <hip/hip_runtime.h>
#include <math.h>
#include <float.h>

#define HW 4096
#define CHW 262144
#define NTOK 65536
#define NELEM 4194304

// ws float offsets
#define WS_LOSS 0        // 1024 floats (per-block loss partials)
#define WS_PART 1024     // 512 doubles = 1024 floats (std partials: S[64][4], S2[64][4])
#define WS_EE   2048     // 1024 (exact fp32 row norms)
#define WS_E2   3072     // 131072 ushorts: codebook hi/lo, frag-contiguous per 64-code tile
#define WS_HIST 68608    // 1024 ints (global histogram)
#define WS_DONE 69632    // 1 int

#define EPSM 1.0e-4f     // certification margin (>=2x worst-case per-score error ~3e-5)

typedef __attribute__((ext_vector_type(8))) short bf16x8;
typedef __attribute__((ext_vector_type(4))) float f32x4;

__device__ __forceinline__ unsigned short f2bf(float x) {
  unsigned u = __float_as_uint(x);
  u += 0x7FFFu + ((u >> 16) & 1u);
  return (unsigned short)(u >> 16);
}
__device__ __forceinline__ float bf2f(unsigned short h) {
  return __uint_as_float(((unsigned)h) << 16);
}
__device__ __forceinline__ void gload_lds16(const unsigned short* g, unsigned short* l) {
  __builtin_amdgcn_global_load_lds(
      (const __attribute__((address_space(1))) unsigned int*)g,
      (__attribute__((address_space(3))) unsigned int*)l, 16, 0, 0);
}

// ---------------- k_pre: blocks 0..255 std partials, 256..271 codebook decompose+swizzle ----
__global__ __launch_bounds__(1024) void k_pre(const float* __restrict__ z,
                                              const float* __restrict__ emb,
                                              double* __restrict__ part,
                                              unsigned short* __restrict__ e2g,
                                              float* __restrict__ eeg,
                                              int* __restrict__ hist,
                                              int* __restrict__ done) {
  __shared__ double rs[16], rs2[16];
  int tid = threadIdx.x;
  int blk = blockIdx.x;
  if (blk == 0 && tid == 0) *done = 0;   // re-init every launch (ws poisoned)
  if (blk < 256) {
    // per-channel std partials over 4 batch-slices (deterministic fixed-order tree)
    int c = blk & 63, q = blk >> 6;
    double s = 0.0, s2 = 0.0;
    const float* base = z + (size_t)c * HW;
    #pragma unroll
    for (int jj = 0; jj < 4; ++jj) {
      int bb = (q << 2) + jj;
      float4 v = *(const float4*)(base + (size_t)bb * CHW + (tid << 2));
      s  += (double)v.x + (double)v.y + (double)v.z + (double)v.w;
      s2 += (double)v.x * v.x + (double)v.y * v.y + (double)v.z * v.z + (double)v.w * v.w;
    }
    for (int o = 32; o > 0; o >>= 1) {
      s += __shfl_down(s, o, 64);
      s2 += __shfl_down(s2, o, 64);
    }
    int wv = tid >> 6, ln = tid & 63;
    if (ln == 0) { rs[wv] = s; rs2[wv] = s2; }
    __syncthreads();
    if (tid == 0) {
      double S = 0.0, S2 = 0.0;
      #pragma unroll
      for (int w = 0; w < 16; ++w) { S += rs[w]; S2 += rs2[w]; }
      part[(c << 2) + q] = S;
      part[256 + (c << 2) + q] = S2;
    }
  } else {
    // 64 codes/tile: bf16 hi|lo decompose into frag-contiguous tile layout
    // e2g[ct][jH(4)][cH(4)][jL(4)][cL(16)][8]  (ushort strides 2048/512/128/8)
    int ct = blk - 256;
    if (ct == 0) hist[tid] = 0;          // zero global histogram (ws poisoned)
    int k0 = ct << 6;
    int code = tid >> 4, c4 = tid & 15;
    float4 v = *(const float4*)(emb + (size_t)((k0 + code) << 6) + (c4 << 2));
    unsigned short h0 = f2bf(v.x), h1 = f2bf(v.y), h2 = f2bf(v.z), h3 = f2bf(v.w);
    unsigned short l0 = f2bf(v.x - bf2f(h0)), l1 = f2bf(v.y - bf2f(h1));
    unsigned short l2 = f2bf(v.z - bf2f(h2)), l3 = f2bf(v.w - bf2f(h3));
    int jL = (c4 >> 1) & 3;
    int e = (c4 & 1) << 2;
    int cH = code >> 4, cL = code & 15;
    size_t base = (size_t)ct * 8192 + cH * 512 + jL * 128 + cL * 8 + e;
    int jHh = c4 >> 3;
    *(uint2*)(e2g + base + (size_t)jHh * 2048) =
        make_uint2((unsigned)h0 | ((unsigned)h1 << 16), (unsigned)h2 | ((unsigned)h3 << 16));
    *(uint2*)(e2g + base + (size_t)(2 + jHh) * 2048) =
        make_uint2((unsigned)l0 | ((unsigned)l1 << 16), (unsigned)l2 | ((unsigned)l3 << 16));
    if (tid < 64) {
      const float* er = emb + (size_t)((k0 + tid) << 6);
      float s = 0.f;
      #pragma unroll
      for (int c = 0; c < 64; ++c) s = fmaf(er[c], er[c], s);
      eeg[k0 + tid] = s;
    }
  }
}

// ---------------- main kernel: 1024 blocks x 64 tokens, MFMA argmin, top-3 certify ---------
// REGISTER DIET for occupancy: the afc[4][4] register cache (64 regs, AGPR-side on gfx950's
// unified RF) made arch+acc ~200 regs/wave -> only 2 blocks/CU resident. Dropped: A-frags
// are re-read from persistent LDS (Ahi/Alo, no DMA aliasing) each tile, slabs reordered
// A-major so each frag is read once/tile. Peak live ~145 regs -> __launch_bounds__(256,3)
// (cap 170) is safe (round-1 spilled because the OLD ~200-reg state exceeded this cap).
// LDS 49.5KB -> 3 blocks/CU. K-loop itself is the round-2-proven barrier-per-tile form.
__global__ __launch_bounds__(256, 3) void k_vq(
    const float* __restrict__ z_e, const float* __restrict__ emb,
    const double* __restrict__ part, const float* __restrict__ eeg,
    const unsigned short* __restrict__ e2g,
    float* __restrict__ out_zq, float* __restrict__ out_idx,
    float* __restrict__ loss_part, int* __restrict__ done,
    float* __restrict__ out_scalars, int* __restrict__ hist) {
  __shared__ unsigned short Ahi[4096];  // 8 KB: z hi frags (persistent, never aliased by DMA)
  __shared__ unsigned short Alo[4096];  // 8 KB: z lo frags
  __shared__ unsigned short B0[8192];   // 16 KB: DMA buffer 0 (scalar scratch aliases later)
  __shared__ unsigned short B1[8192];   // 16 KB: DMA buffer 1
  __shared__ float sRstd[64];
  __shared__ double rl[4], rh[4];
  __shared__ int lastFlag;
  // scalar scratch aliased onto B0 after the MFMA loop (B0 dead then; last tile uses B1):
  float* hs1 = (float*)B0;               // [4][64]
  float* hs2 = (float*)B0 + 256;
  float* hs3 = (float*)B0 + 512;
  int*   hk1 = (int*)B0 + 768;
  int*   hk2 = (int*)B0 + 1024;
  int*   skf = (int*)B0 + 1280;          // [64]
  int*   mk2f = (int*)B0 + 1344;         // [64]
  int*   pairL = (int*)B0 + 1408;        // [64]
  int*   fullL = (int*)B0 + 1472;        // [64]
  int*   cntB = (int*)B0 + 1536;
  int*   cntC = (int*)B0 + 1537;
  float* sred = (float*)B0 + 1540;       // [4]
  float* zf   = (float*)B0 + 1544;       // [64] (16B-aligned: 1544*4=6176)
  float* fbd4 = (float*)B0 + 1608;
  int*   fbk4 = (int*)B0 + 1612;

  int tid = threadIdx.x;
  int lane = tid & 63;
  int wv = tid >> 6;
  int blk = blockIdx.x;            // 1024 blocks
  int b = blk >> 6;
  int s0 = (blk & 63) << 6;

  // DMA tile 0 into buffer 0 (B0) — issued first, overlaps the whole prologue
  {
    const unsigned short* gsrc = e2g + wv * 512 + (lane << 3);
    unsigned short* ldst = B0 + wv * 512;
    #pragma unroll
    for (int rr = 0; rr < 4; ++rr)
      gload_lds16(gsrc + rr * 2048, ldst + rr * 2048);
  }

  // ---- rstd from deterministic partials (fixed summation order) ----
  if (tid < 64) {
    double S = 0.0, S2 = 0.0;
    #pragma unroll
    for (int q = 0; q < 4; ++q) {
      S += part[(tid << 2) + q];
      S2 += part[256 + (tid << 2) + q];
    }
    const double N = (double)NTOK;
    double var = (S2 - S * S / N) / (N - 1.0);
    float sd = fmaxf((float)sqrt(var), 1e-5f);
    sRstd[tid] = 1.0f / sd;
  }
  __syncthreads();   // sRstd ready (also drains DMA0 early — harmless)

  // ---- stage A: normalize (mul by rstd) + hi/lo decompose, frag layout ----
  // Ahi[jH(2)][tT(4)][jL(4)][tL(16)][8], Alo same (ushort strides 2048/512/128/8)
  {
    int t = tid & 63, q = tid >> 6;            // q uniform per wave -> broadcast rstd reads
    int half = q >> 1, jl0 = (q & 1) << 1;
    const float* zsrc = z_e + (size_t)b * CHW + (size_t)(q << 4) * HW + s0 + t;
    unsigned hw_[8], lw_[8];
    #pragma unroll
    for (int cc = 0; cc < 16; ++cc) {
      float v = zsrc[(size_t)cc * HW] * sRstd[(q << 4) + cc];
      unsigned short h = f2bf(v);
      unsigned short l = f2bf(v - bf2f(h));
      if (cc & 1) { hw_[cc >> 1] |= ((unsigned)h) << 16; lw_[cc >> 1] |= ((unsigned)l) << 16; }
      else        { hw_[cc >> 1] = h;                    lw_[cc >> 1] = l; }
    }
    int base = (t >> 4) * 512 + (t & 15) * 8;
    #pragma unroll
    for (int u = 0; u < 2; ++u) {
      *(uint4*)(Ahi + half * 2048 + base + (jl0 + u) * 128) =
          make_uint4(hw_[4 * u], hw_[4 * u + 1], hw_[4 * u + 2], hw_[4 * u + 3]);
      *(uint4*)(Alo + half * 2048 + base + (jl0 + u) * 128) =
          make_uint4(lw_[4 * u], lw_[4 * u + 1], lw_[4 * u + 2], lw_[4 * u + 3]);
    }
  }
  __syncthreads();   // Ahi/Alo ready; DMA0 drained

  int quad = lane >> 4, l15 = lane & 15;

  // top-3 state per token-slot; wave wv owns code slice {k : (k>>4)&3 == wv}
  float ts1[16], ts2[16], ts3[16];
  int tk1[16], tk2[16];
  #pragma unroll
  for (int i = 0; i < 16; ++i) { ts1[i] = FLT_MAX; ts2[i] = FLT_MAX; ts3[i] = FLT_MAX; tk1[i] = 0; tk2[i] = 0; }

  // Slab plan, A-major order (each A-frag set read from LDS once per tile, held transiently):
  //   j=0: A=hi half0, B jH {0,2};  j=1: A=hi half1, B jH {1,3};
  //   j=2: A=lo half0, B jH {0,2};  j=3: A=lo half1, B jH {1,3}.
  // Same 8 slabs as before, accumulation order permuted (~1ulp; certified via EPSM).
  #pragma unroll 1
  for (int ct = 0; ct < 16; ++ct) {
    const unsigned short* bb = (ct & 1) ? B1 : B0;
    if (ct < 15) {     // DMA next tile into other buffer; drained at end-of-iter barrier
      const unsigned short* gsrc = e2g + (size_t)(ct + 1) * 8192 + wv * 512 + (lane << 3);
      unsigned short* ldst = (((ct + 1) & 1) ? B1 : B0) + wv * 512;
      #pragma unroll
      for (int rr = 0; rr < 4; ++rr)
        gload_lds16(gsrc + rr * 2048, ldst + rr * 2048);
    }
    float ee0 = eeg[(ct << 6) + (wv << 4) + l15];

    f32x4 acc[4];
    #pragma unroll
    for (int mt = 0; mt < 4; ++mt) acc[mt] = (f32x4)(0.f);

    #pragma unroll
    for (int j = 0; j < 4; ++j) {
      const unsigned short* ab = (j < 2) ? (Ahi + j * 2048) : (Alo + (j - 2) * 2048);
      bf16x8 af[4];
      #pragma unroll
      for (int mt = 0; mt < 4; ++mt)
        af[mt] = *(const bf16x8*)(ab + mt * 512 + quad * 128 + l15 * 8);
      bf16x8 bfr0 = *(const bf16x8*)(bb + (j & 1) * 2048 + wv * 512 + quad * 128 + l15 * 8);
      bf16x8 bfr1 = *(const bf16x8*)(bb + ((j & 1) + 2) * 2048 + wv * 512 + quad * 128 + l15 * 8);
      #pragma unroll
      for (int mt = 0; mt < 4; ++mt)
        acc[mt] = __builtin_amdgcn_mfma_f32_16x16x32_bf16(af[mt], bfr0, acc[mt], 0, 0, 0);
      #pragma unroll
      for (int mt = 0; mt < 4; ++mt)
        acc[mt] = __builtin_amdgcn_mfma_f32_16x16x32_bf16(af[mt], bfr1, acc[mt], 0, 0, 0);
    }

    // eval: s = ee - 2*dot ; top-3 insertion via med3 (k ascending across ct within lane)
    int kc = (ct << 6) + (wv << 4) + l15;
    #pragma unroll
    for (int mt = 0; mt < 4; ++mt) {
      #pragma unroll
      for (int r = 0; r < 4; ++r) {
        float sv = fmaf(-2.0f, acc[mt][r], ee0);
        int sl = (mt << 2) + r;
        bool lt1 = sv < ts1[sl];
        bool lt2 = sv < ts2[sl];
        ts3[sl] = fminf(fmaxf(sv, ts2[sl]), ts3[sl]);   // med3(sv, ts2, ts3)
        tk2[sl] = lt1 ? tk1[sl] : (lt2 ? kc : tk2[sl]);
        ts2[sl] = fminf(fmaxf(sv, ts1[sl]), ts2[sl]);   // med3(sv, ts1, ts2)
        tk1[sl] = lt1 ? kc : tk1[sl];
        ts1[sl] = fminf(sv, ts1[sl]);
      }
    }
    if (ct < 15) __syncthreads();   // drain DMA(ct+1); all waves done with bb
  }
  __syncthreads();   // B0/B1 dead; alias region live

  // merge top-3 across the 16 cols (lane&15) via xor-shuffles; (s,k)-lex ties
  #pragma unroll
  for (int m = 1; m <= 8; m <<= 1) {
    #pragma unroll
    for (int sl = 0; sl < 16; ++sl) {
      float ob1 = __shfl_xor(ts1[sl], m, 64); int oq1 = __shfl_xor(tk1[sl], m, 64);
      float ob2 = __shfl_xor(ts2[sl], m, 64); int oq2 = __shfl_xor(tk2[sl], m, 64);
      float ob3 = __shfl_xor(ts3[sl], m, 64);
      bool t1 = (ts1[sl] < ob1) || (ts1[sl] == ob1 && tk1[sl] < oq1);
      float o1 = t1 ? ts1[sl] : ob1; int ok1 = t1 ? tk1[sl] : oq1;
      float aH = t1 ? ts2[sl] : ts1[sl]; int aHk = t1 ? tk2[sl] : tk1[sl]; float aH2 = t1 ? ts3[sl] : ts2[sl];
      float bH = t1 ? ob1 : ob2;         int bHk = t1 ? oq1 : oq2;         float bH2 = t1 ? ob2 : ob3;
      bool t2 = (aH < bH) || (aH == bH && aHk < bHk);
      float o2 = t2 ? aH : bH; int ok2 = t2 ? aHk : bHk;
      float aI = t2 ? aH2 : aH;
      float bI = t2 ? bH : bH2;
      ts1[sl] = o1; tk1[sl] = ok1; ts2[sl] = o2; tk2[sl] = ok2; ts3[sl] = fminf(aI, bI);
    }
  }
  if (tid == 0) { *cntB = 0; *cntC = 0; }
  if (l15 == 0) {
    #pragma unroll
    for (int mt = 0; mt < 4; ++mt)
      #pragma unroll
      for (int r = 0; r < 4; ++r) {
        int t = (mt << 4) + (quad << 2) + r;
        int sl = (mt << 2) + r;
        hs1[(wv << 6) + t] = ts1[sl]; hs2[(wv << 6) + t] = ts2[sl]; hs3[(wv << 6) + t] = ts3[sl];
        hk1[(wv << 6) + t] = tk1[sl]; hk2[(wv << 6) + t] = tk2[sl];
      }
  }
  __syncthreads();

  // 4-way cross-wave merge + classification
  if (tid < 64) {
    float a1 = hs1[tid], a2 = hs2[tid], a3 = hs3[tid];
    int e1 = hk1[tid], e2v = hk2[tid];
    #pragma unroll
    for (int w = 1; w < 4; ++w) {
      float b1 = hs1[(w << 6) + tid], b2 = hs2[(w << 6) + tid], b3 = hs3[(w << 6) + tid];
      int f1 = hk1[(w << 6) + tid], f2 = hk2[(w << 6) + tid];
      bool t1 = (a1 < b1) || (a1 == b1 && e1 < f1);
      float o1 = t1 ? a1 : b1; int ok1 = t1 ? e1 : f1;
      float aH = t1 ? a2 : a1; int aHk = t1 ? e2v : e1; float aH2 = t1 ? a3 : a2;
      float bH = t1 ? b1 : b2; int bHk = t1 ? f1 : f2; float bH2 = t1 ? b2 : b3;
      bool t2 = (aH < bH) || (aH == bH && aHk < bHk);
      a1 = o1; e1 = ok1;
      a2 = t2 ? aH : bH; e2v = t2 ? aHk : bHk;
      a3 = fminf(t2 ? aH2 : aH, t2 ? bH : bH2);
    }
    skf[tid] = e1;
    mk2f[tid] = e2v;
    if (a2 - a1 <= EPSM) {
      if (a3 - a1 > EPSM) { int p = atomicAdd(cntB, 1); pairL[p] = tid; }
      else                { int p = atomicAdd(cntC, 1); fullL[p] = tid; }
    }
  }
  __syncthreads();

  int nB = *cntB, nC = *cntC;

  // ---- case B: exact pairwise compare {k1,k2}, one thread per token ----
  if (tid < nB) {
    int t = pairL[tid];
    int ka = skf[t], kb = mk2f[t];
    const float* za = z_e + (size_t)b * CHW + s0 + t;
    const float* ea = emb + ((size_t)ka << 6);
    const float* ebp = emb + ((size_t)kb << 6);
    float zz = 0.f, da = 0.f, db = 0.f;
    #pragma unroll
    for (int c = 0; c < 64; ++c) {
      float zv = za[(size_t)c * HW] * sRstd[c];
      zz = fmaf(zv, zv, zz);
      da = fmaf(ea[c], zv, da);
      db = fmaf(ebp[c], zv, db);
    }
    float d1 = (zz - 2.0f * da) + eeg[ka];
    float d2 = (zz - 2.0f * db) + eeg[kb];
    if (d2 < d1 || (d2 == d1 && kb < ka)) skf[t] = kb;
  }
  __syncthreads();

  // ---- case C (rare): block-cooperative full scan, exact formula ----
  for (int i = 0; i < nC; ++i) {
    int t = fullL[i];
    if (tid < 64) zf[tid] = z_e[(size_t)b * CHW + (size_t)tid * HW + s0 + t] * sRstd[tid];
    __syncthreads();
    const float4* zf4 = (const float4*)zf;
    const float* er0 = emb + ((size_t)(tid << 2) << 6);
    float zz = 0.f;
    float dot[4] = {0.f, 0.f, 0.f, 0.f};
    #pragma unroll
    for (int c4 = 0; c4 < 16; ++c4) {
      float4 zv = zf4[c4];
      zz = fmaf(zv.x, zv.x, zz); zz = fmaf(zv.y, zv.y, zz);
      zz = fmaf(zv.z, zv.z, zz); zz = fmaf(zv.w, zv.w, zz);
      #pragma unroll
      for (int j = 0; j < 4; ++j) {
        float4 ev = *(const float4*)(er0 + (j << 6) + (c4 << 2));
        dot[j] = fmaf(ev.x, zv.x, dot[j]);
        dot[j] = fmaf(ev.y, zv.y, dot[j]);
        dot[j] = fmaf(ev.z, zv.z, dot[j]);
        dot[j] = fmaf(ev.w, zv.w, dot[j]);
      }
    }
    float bdl = FLT_MAX; int bkl = 0;
    #pragma unroll
    for (int j = 0; j < 4; ++j) {
      float dd = (zz - 2.0f * dot[j]) + eeg[(tid << 2) + j];
      if (dd < bdl) { bdl = dd; bkl = (tid << 2) + j; }
    }
    #pragma unroll
    for (int m = 1; m <= 32; m <<= 1) {
      float od = __shfl_xor(bdl, m, 64);
      int   ok = __shfl_xor(bkl, m, 64);
      if (od < bdl || (od == bdl && ok < bkl)) { bdl = od; bkl = ok; }
    }
    if (lane == 0) { fbd4[wv] = bdl; fbk4[wv] = bkl; }
    __syncthreads();
    if (tid == 0) {
      float bb2 = fbd4[0]; int kk2 = fbk4[0];
      #pragma unroll
      for (int w = 1; w < 4; ++w)
        if (fbd4[w] < bb2 || (fbd4[w] == bb2 && fbk4[w] < kk2)) { bb2 = fbd4[w]; kk2 = fbk4[w]; }
      skf[t] = kk2;
    }
    __syncthreads();
  }
  __syncthreads();

  if (tid < 64) {
    int k = skf[tid];
    out_idx[(blk << 6) + tid] = (float)k;
    atomicAdd(&hist[k], 1);      // distributed histogram (no serial tail re-read)
  }

  // ---- epilogue: z recomputed bit-consistently from global, coalesced stores ----
  {
    int t = tid & 63;
    int g = tid >> 6;
    int kq = skf[t];
    const float* eq = emb + ((size_t)kq << 6) + (g << 4);
    const float* zb2 = z_e + (size_t)b * CHW + (size_t)(g << 4) * HW + s0 + t;
    float* ob = out_zq + (size_t)b * CHW + (size_t)(g << 4) * HW + s0 + t;
    float lsum = 0.f;
    #pragma unroll
    for (int j4 = 0; j4 < 4; ++j4) {
      float4 ev = *(const float4*)(eq + (j4 << 2));
      #pragma unroll
      for (int u = 0; u < 4; ++u) {
        int jj = (j4 << 2) + u;
        float zv = zb2[(size_t)jj * HW] * sRstd[(g << 4) + jj];
        float e = (&ev.x)[u];
        float df = zv - e;
        lsum = fmaf(df, df, lsum);
        ob[(size_t)jj * HW] = zv + (e - zv);
      }
    }
    for (int o = 32; o > 0; o >>= 1) lsum += __shfl_down(lsum, o, 64);
    if (lane == 0) sred[wv] = lsum;
  }
  __syncthreads();

  // ---- fused finalize via done-counter (validated pattern); tail is tiny ----
  if (tid == 0) {
    loss_part[blk] = sred[0] + sred[1] + sred[2] + sred[3];
    __threadfence();
    int prev = atomicAdd(done, 1);
    lastFlag = (prev == 1023);
  }
  __syncthreads();
  if (!lastFlag) return;

  double ls = (double)loss_part[tid] + (double)loss_part[tid + 256]
            + (double)loss_part[tid + 512] + (double)loss_part[tid + 768];
  double hsum = 0.0;
  #pragma unroll
  for (int jj = 0; jj < 4; ++jj) {
    float p = (float)hist[tid + (jj << 8)] * (1.0f / 65536.0f);
    float lg = logf(fmaxf(p, 1e-10f));
    hsum += (double)(p * lg);
  }
  for (int o = 32; o > 0; o >>= 1) {
    ls += __shfl_down(ls, o, 64);
    hsum += __shfl_down(hsum, o, 64);
  }
  if (lane == 0) { rl[wv] = ls; rh[wv] = hsum; }
  __syncthreads();
  if (tid == 0) {
    double L = rl[0] + rl[1] + rl[2] + rl[3];
    double Hn = rh[0] + rh[1] + rh[2] + rh[3];
    float m = (float)(L / (double)NELEM);
    out_scalars[0] = 0.25f * m + m;
    out_scalars[1] = expf((float)(-Hn));
  }
}

extern "C" void kernel_launch(void* const* d_in, const int* in_sizes, int n_in,
                              void* d_out, int out_size, void* d_ws, size_t ws_size,
                              hipStream_t stream) {
  const float* z_e = (const float*)d_in[0];
  const float* emb = (const float*)d_in[1];
  float* ws = (float*)d_ws;
  float* loss_part = ws + WS_LOSS;
  double* part = (double*)(ws + WS_PART);
  float* eeg = ws + WS_EE;
  unsigned short* e2g = (unsigned short*)(ws + WS_E2);
  int* hist = (int*)(ws + WS_HIST);
  int* done = (int*)(ws + WS_DONE);     // ws use ~279 KB

  float* out = (float*)d_out;
  float* out_zq = out;                  // 4194304
  float* out_scalars = out + NELEM;     // vq_loss, perplexity
  float* out_idx = out + NELEM + 2;     // 65536 indices as float

  k_pre<<<272, 1024, 0, stream>>>(z_e, emb, part, e2g, eeg, hist, done);
  k_vq<<<1024, 256, 0, stream>>>(z_e, emb, part, eeg, e2g, out_zq, out_idx,
                                 loss_part, done, out_scalars, hist);
}

// Round 6
// 193.014 us; speedup vs baseline: 1.4792x; 1.4792x over previous
//
#include <hip/hip_runtime.h>
#include <math.h>
#include <float.h>

#define HW 4096
#define CHW 262144
#define NTOK 65536
#define NELEM 4194304

// ws float offsets
#define WS_LOSS 0        // 1024 floats (per-block loss partials)
#define WS_PART 1024     // 512 doubles = 1024 floats (std partials: S[64][4], S2[64][4])
#define WS_EE   2048     // 1024 (exact fp32 row norms)
#define WS_E2   3072     // 131072 ushorts: codebook hi/lo, frag-contiguous per 64-code tile
#define WS_HIST 68608    // 1024 ints (global histogram)
#define WS_DONE 69632    // 1 int

// Certification margin. Per-score deviation of the packed MFMA path from the exact fp32
// score: mfma hi/lo error ~3e-5 + dropped lo*lo slabs <=1.2e-5 + 4-bit pack truncation
// <=1.5e-5 + bias rounding ~4e-6  => ~6e-5 total; EPSM >= 2x that.
#define EPSM 2.0e-4f

typedef __attribute__((ext_vector_type(8))) short bf16x8;
typedef __attribute__((ext_vector_type(4))) float f32x4;

__device__ __forceinline__ unsigned short f2bf(float x) {
  unsigned u = __float_as_uint(x);
  u += 0x7FFFu + ((u >> 16) & 1u);
  return (unsigned short)(u >> 16);
}
__device__ __forceinline__ float bf2f(unsigned short h) {
  return __uint_as_float(((unsigned)h) << 16);
}
__device__ __forceinline__ void gload_lds16(const unsigned short* g, unsigned short* l) {
  __builtin_amdgcn_global_load_lds(
      (const __attribute__((address_space(1))) unsigned int*)g,
      (__attribute__((address_space(3))) unsigned int*)l, 16, 0, 0);
}

// ---------------- k_pre: blocks 0..255 std partials, 256..271 codebook decompose+swizzle ----
__global__ __launch_bounds__(1024) void k_pre(const float* __restrict__ z,
                                              const float* __restrict__ emb,
                                              double* __restrict__ part,
                                              unsigned short* __restrict__ e2g,
                                              float* __restrict__ eeg,
                                              int* __restrict__ hist,
                                              int* __restrict__ done) {
  __shared__ double rs[16], rs2[16];
  int tid = threadIdx.x;
  int blk = blockIdx.x;
  if (blk == 0 && tid == 0) *done = 0;   // re-init every launch (ws poisoned)
  if (blk < 256) {
    // per-channel std partials over 4 batch-slices (deterministic fixed-order tree)
    int c = blk & 63, q = blk >> 6;
    double s = 0.0, s2 = 0.0;
    const float* base = z + (size_t)c * HW;
    #pragma unroll
    for (int jj = 0; jj < 4; ++jj) {
      int bb = (q << 2) + jj;
      float4 v = *(const float4*)(base + (size_t)bb * CHW + (tid << 2));
      s  += (double)v.x + (double)v.y + (double)v.z + (double)v.w;
      s2 += (double)v.x * v.x + (double)v.y * v.y + (double)v.z * v.z + (double)v.w * v.w;
    }
    for (int o = 32; o > 0; o >>= 1) {
      s += __shfl_down(s, o, 64);
      s2 += __shfl_down(s2, o, 64);
    }
    int wv = tid >> 6, ln = tid & 63;
    if (ln == 0) { rs[wv] = s; rs2[wv] = s2; }
    __syncthreads();
    if (tid == 0) {
      double S = 0.0, S2 = 0.0;
      #pragma unroll
      for (int w = 0; w < 16; ++w) { S += rs[w]; S2 += rs2[w]; }
      part[(c << 2) + q] = S;
      part[256 + (c << 2) + q] = S2;
    }
  } else {
    // 64 codes/tile: bf16 hi|lo decompose into frag-contiguous tile layout
    // e2g[ct][jH(4)][cH(4)][jL(4)][cL(16)][8]  (ushort strides 2048/512/128/8)
    int ct = blk - 256;
    if (ct == 0) hist[tid] = 0;          // zero global histogram (ws poisoned)
    int k0 = ct << 6;
    int code = tid >> 4, c4 = tid & 15;
    float4 v = *(const float4*)(emb + (size_t)((k0 + code) << 6) + (c4 << 2));
    unsigned short h0 = f2bf(v.x), h1 = f2bf(v.y), h2 = f2bf(v.z), h3 = f2bf(v.w);
    unsigned short l0 = f2bf(v.x - bf2f(h0)), l1 = f2bf(v.y - bf2f(h1));
    unsigned short l2 = f2bf(v.z - bf2f(h2)), l3 = f2bf(v.w - bf2f(h3));
    int jL = (c4 >> 1) & 3;
    int e = (c4 & 1) << 2;
    int cH = code >> 4, cL = code & 15;
    size_t base = (size_t)ct * 8192 + cH * 512 + jL * 128 + cL * 8 + e;
    int jHh = c4 >> 3;
    *(uint2*)(e2g + base + (size_t)jHh * 2048) =
        make_uint2((unsigned)h0 | ((unsigned)h1 << 16), (unsigned)h2 | ((unsigned)h3 << 16));
    *(uint2*)(e2g + base + (size_t)(2 + jHh) * 2048) =
        make_uint2((unsigned)l0 | ((unsigned)l1 << 16), (unsigned)l2 | ((unsigned)l3 << 16));
    if (tid < 64) {
      const float* er = emb + (size_t)((k0 + tid) << 6);
      float s = 0.f;
      #pragma unroll
      for (int c = 0; c < 64; ++c) s = fmaf(er[c], er[c], s);
      eeg[k0 + tid] = s;
    }
  }
}

// ---------------- main kernel: 1024 blocks x 64 tokens, MFMA argmin, top-3 certify ---------
// Base = the proven 131us round-2 structure: barrier-per-tile K-loop, afc register cache,
// __launch_bounds__(256,2) (min-waves=3 spills catastrophically — measured twice).
// NEW: packed score+index top-3. Scores biased positive (ee+8; |score|<=~5 provable, plus a
// fmax(0.25) clamp whose only failure mode collapses marginal scores into the exact case-B/C
// fallback), low 4 mantissa bits overwritten with ct. Positive-float min/med3 on packed
// values IS the (score, k)-lex top-3: no index arrays in the loop (-32 VGPR, ~-5 VALU/score).
// Also dropped the 2 lo*lo slabs (contribution <=1.2e-5): 24 MFMA + 6 ds_read per tile.
__global__ __launch_bounds__(256, 2) void k_vq(
    const float* __restrict__ z_e, const float* __restrict__ emb,
    const double* __restrict__ part, const float* __restrict__ eeg,
    const unsigned short* __restrict__ e2g,
    float* __restrict__ out_zq, float* __restrict__ out_idx,
    float* __restrict__ loss_part, int* __restrict__ done,
    float* __restrict__ out_scalars, int* __restrict__ hist) {
  __shared__ unsigned short A2[8192];   // 16 KB: z hi/lo frag-contiguous; aliased after afc load
  __shared__ unsigned short B2[8192];   // 16 KB: DMA buffer 0
  __shared__ float sEE[1024];           // 4 KB: code row-norms + 8.0 bias
  __shared__ float sRstd[64];
  __shared__ double rl[4], rh[4];
  __shared__ int lastFlag;
  // scalar scratch aliased onto A2 after the MFMA loop (A2/buf1 dead then):
  float* hs1 = (float*)A2;               // [4][64]
  float* hs2 = (float*)A2 + 256;
  float* hs3 = (float*)A2 + 512;
  int*   hk1 = (int*)A2 + 768;
  int*   hk2 = (int*)A2 + 1024;
  int*   skf = (int*)A2 + 1280;          // [64]
  int*   mk2f = (int*)A2 + 1344;         // [64]
  int*   pairL = (int*)A2 + 1408;        // [64]
  int*   fullL = (int*)A2 + 1472;        // [64]
  int*   cntB = (int*)A2 + 1536;
  int*   cntC = (int*)A2 + 1537;
  float* sred = (float*)A2 + 1540;       // [4]
  float* zf   = (float*)A2 + 1544;       // [64] (16B-aligned: 1544*4=6176)
  float* fbd4 = (float*)A2 + 1608;
  int*   fbk4 = (int*)A2 + 1612;

  int tid = threadIdx.x;
  int lane = tid & 63;
  int wv = tid >> 6;
  int blk = blockIdx.x;            // 1024 blocks
  int b = blk >> 6;
  int s0 = (blk & 63) << 6;

  // eeg -> LDS with +8 bias (keeps packed scores positive; bias cancels in all gap tests)
  {
    float4 ev = ((const float4*)eeg)[tid];
    ev.x += 8.0f; ev.y += 8.0f; ev.z += 8.0f; ev.w += 8.0f;
    ((float4*)sEE)[tid] = ev;
  }

  // ---- rstd from deterministic partials (fixed summation order) ----
  if (tid < 64) {
    double S = 0.0, S2 = 0.0;
    #pragma unroll
    for (int q = 0; q < 4; ++q) {
      S += part[(tid << 2) + q];
      S2 += part[256 + (tid << 2) + q];
    }
    const double N = (double)NTOK;
    double var = (S2 - S * S / N) / (N - 1.0);
    float sd = fmaxf((float)sqrt(var), 1e-5f);
    sRstd[tid] = 1.0f / sd;
  }
  __syncthreads();   // sRstd + sEE ready

  // ---- stage A: normalize (mul by rstd) + hi/lo decompose, frag layout ----
  // A2[jH(4)][tT(4)][jL(4)][tL(16)][8]: ushort strides 2048/512/128/8
  {
    int t = tid & 63, q = tid >> 6;            // q uniform per wave -> broadcast rstd reads
    int half = q >> 1, jl0 = (q & 1) << 1;
    const float* zsrc = z_e + (size_t)b * CHW + (size_t)(q << 4) * HW + s0 + t;
    unsigned hw_[8], lw_[8];
    #pragma unroll
    for (int cc = 0; cc < 16; ++cc) {
      float v = zsrc[(size_t)cc * HW] * sRstd[(q << 4) + cc];
      unsigned short h = f2bf(v);
      unsigned short l = f2bf(v - bf2f(h));
      if (cc & 1) { hw_[cc >> 1] |= ((unsigned)h) << 16; lw_[cc >> 1] |= ((unsigned)l) << 16; }
      else        { hw_[cc >> 1] = h;                    lw_[cc >> 1] = l; }
    }
    int base = (t >> 4) * 512 + (t & 15) * 8;
    #pragma unroll
    for (int u = 0; u < 2; ++u) {
      *(uint4*)(A2 + half * 2048 + base + (jl0 + u) * 128) =
          make_uint4(hw_[4 * u], hw_[4 * u + 1], hw_[4 * u + 2], hw_[4 * u + 3]);
      *(uint4*)(A2 + (2 + half) * 2048 + base + (jl0 + u) * 128) =
          make_uint4(lw_[4 * u], lw_[4 * u + 1], lw_[4 * u + 2], lw_[4 * u + 3]);
    }
  }

  int quad = lane >> 4, l15 = lane & 15;

  // DMA tile 0 into buffer 0 (B2)
  {
    const unsigned short* gsrc = e2g + wv * 512 + (lane << 3);
    unsigned short* ldst = B2 + wv * 512;
    #pragma unroll
    for (int rr = 0; rr < 4; ++rr)
      gload_lds16(gsrc + rr * 2048, ldst + rr * 2048);
  }
  __syncthreads();   // A2 ready + DMA0 drained

  // A-fragments: loop-invariant -> cache in registers (16 b128, read once)
  bf16x8 afc[4][4];
  #pragma unroll
  for (int j = 0; j < 4; ++j)
    #pragma unroll
    for (int mt = 0; mt < 4; ++mt)
      afc[j][mt] = *(const bf16x8*)(A2 + j * 2048 + mt * 512 + quad * 128 + l15 * 8);
  __syncthreads();   // all afc reads drained before anyone's DMA1 lands in A2 (alias safety)

  // packed top-3 state per token-slot; wave wv owns code slice {k : (k>>4)&3 == wv};
  // within a lane only ct (4 bits) varies -> packed into the low 4 mantissa bits.
  float ts1[16], ts2[16], ts3[16];
  #pragma unroll
  for (int i = 0; i < 16; ++i) { ts1[i] = FLT_MAX; ts2[i] = FLT_MAX; ts3[i] = FLT_MAX; }

  // slab plan: (zh+zl)*(eh+el) minus the lo*lo terms, K'=256
  const int aJH[6] = {0, 1, 2, 3, 0, 1};
  const int bJH[6] = {0, 1, 0, 1, 2, 3};

  #pragma unroll 1
  for (int ct = 0; ct < 16; ++ct) {
    const unsigned short* bb = (ct & 1) ? A2 : B2;
    if (ct < 15) {     // DMA next tile into other buffer; drained at end-of-iter barrier
      const unsigned short* gsrc = e2g + (size_t)(ct + 1) * 8192 + wv * 512 + (lane << 3);
      unsigned short* ldst = (((ct + 1) & 1) ? A2 : B2) + wv * 512;
      #pragma unroll
      for (int rr = 0; rr < 4; ++rr)
        gload_lds16(gsrc + rr * 2048, ldst + rr * 2048);
    }
    float ee0 = sEE[(ct << 6) + (wv << 4) + l15];   // biased +8

    f32x4 acc[4];
    #pragma unroll
    for (int mt = 0; mt < 4; ++mt) acc[mt] = (f32x4)(0.f);

    #pragma unroll
    for (int s = 0; s < 6; ++s) {
      bf16x8 bfr = *(const bf16x8*)(bb + bJH[s] * 2048 + wv * 512 + quad * 128 + l15 * 8);
      #pragma unroll
      for (int mt = 0; mt < 4; ++mt)
        acc[mt] = __builtin_amdgcn_mfma_f32_16x16x32_bf16(afc[aJH[s]][mt], bfr, acc[mt], 0, 0, 0);
    }

    // eval: packed s = ((ee+8) - 2*dot) clamped, low 4 bits := ct; min/med3 = lex top-3
    unsigned ctu = (unsigned)ct;
    #pragma unroll
    for (int mt = 0; mt < 4; ++mt) {
      #pragma unroll
      for (int r = 0; r < 4; ++r) {
        float sv = fmaf(-2.0f, acc[mt][r], ee0);
        sv = fmaxf(sv, 0.25f);   // safety: if this ever fires, ties collapse into case B/C
        float p = __uint_as_float((__float_as_uint(sv) & 0xFFFFFFF0u) | ctu);
        int sl = (mt << 2) + r;
        float t1o = ts1[sl], t2o = ts2[sl];
        ts1[sl] = fminf(p, t1o);
        ts2[sl] = fminf(fmaxf(p, t1o), t2o);          // med3(p, t1o, t2o)
        ts3[sl] = fminf(fmaxf(p, t2o), ts3[sl]);      // med3(p, t2o, t3o)
      }
    }
    if (ct < 15) __syncthreads();   // drain DMA(ct+1); all waves done with bb
  }
  __syncthreads();   // A2/B2 dead; alias region live

  // unpack: k = (ct<<6)|(wv<<4)|l15 ; strip index bits from values (ties then k-lex clean)
  int tk1[16], tk2[16];
  #pragma unroll
  for (int sl = 0; sl < 16; ++sl) {
    unsigned b1 = __float_as_uint(ts1[sl]);
    unsigned b2 = __float_as_uint(ts2[sl]);
    tk1[sl] = (int)(((b1 & 15u) << 6) | ((unsigned)wv << 4) | (unsigned)l15);
    tk2[sl] = (int)(((b2 & 15u) << 6) | ((unsigned)wv << 4) | (unsigned)l15);
    ts1[sl] = __uint_as_float(b1 & ~15u);
    ts2[sl] = __uint_as_float(b2 & ~15u);
    ts3[sl] = __uint_as_float(__float_as_uint(ts3[sl]) & ~15u);
  }

  // merge top-3 across the 16 cols (lane&15) via xor-shuffles; (s,k)-lex ties
  #pragma unroll
  for (int m = 1; m <= 8; m <<= 1) {
    #pragma unroll
    for (int sl = 0; sl < 16; ++sl) {
      float ob1 = __shfl_xor(ts1[sl], m, 64); int oq1 = __shfl_xor(tk1[sl], m, 64);
      float ob2 = __shfl_xor(ts2[sl], m, 64); int oq2 = __shfl_xor(tk2[sl], m, 64);
      float ob3 = __shfl_xor(ts3[sl], m, 64);
      bool t1 = (ts1[sl] < ob1) || (ts1[sl] == ob1 && tk1[sl] < oq1);
      float o1 = t1 ? ts1[sl] : ob1; int ok1 = t1 ? tk1[sl] : oq1;
      float aH = t1 ? ts2[sl] : ts1[sl]; int aHk = t1 ? tk2[sl] : tk1[sl]; float aH2 = t1 ? ts3[sl] : ts2[sl];
      float bH = t1 ? ob1 : ob2;         int bHk = t1 ? oq1 : oq2;         float bH2 = t1 ? ob2 : ob3;
      bool t2 = (aH < bH) || (aH == bH && aHk < bHk);
      float o2 = t2 ? aH : bH; int ok2 = t2 ? aHk : bHk;
      float aI = t2 ? aH2 : aH;
      float bI = t2 ? bH : bH2;
      ts1[sl] = o1; tk1[sl] = ok1; ts2[sl] = o2; tk2[sl] = ok2; ts3[sl] = fminf(aI, bI);
    }
  }
  if (tid == 0) { *cntB = 0; *cntC = 0; }
  if (l15 == 0) {
    #pragma unroll
    for (int mt = 0; mt < 4; ++mt)
      #pragma unroll
      for (int r = 0; r < 4; ++r) {
        int t = (mt << 4) + (quad << 2) + r;
        int sl = (mt << 2) + r;
        hs1[(wv << 6) + t] = ts1[sl]; hs2[(wv << 6) + t] = ts2[sl]; hs3[(wv << 6) + t] = ts3[sl];
        hk1[(wv << 6) + t] = tk1[sl]; hk2[(wv << 6) + t] = tk2[sl];
      }
  }
  __syncthreads();

  // 4-way cross-wave merge + classification
  if (tid < 64) {
    float a1 = hs1[tid], a2 = hs2[tid], a3 = hs3[tid];
    int e1 = hk1[tid], e2v = hk2[tid];
    #pragma unroll
    for (int w = 1; w < 4; ++w) {
      float b1 = hs1[(w << 6) + tid], b2 = hs2[(w << 6) + tid], b3 = hs3[(w << 6) + tid];
      int f1 = hk1[(w << 6) + tid], f2 = hk2[(w << 6) + tid];
      bool t1 = (a1 < b1) || (a1 == b1 && e1 < f1);
      float o1 = t1 ? a1 : b1; int ok1 = t1 ? e1 : f1;
      float aH = t1 ? a2 : a1; int aHk = t1 ? e2v : e1; float aH2 = t1 ? a3 : a2;
      float bH = t1 ? b1 : b2; int bHk = t1 ? f1 : f2; float bH2 = t1 ? b2 : b3;
      bool t2 = (aH < bH) || (aH == bH && aHk < bHk);
      a1 = o1; e1 = ok1;
      a2 = t2 ? aH : bH; e2v = t2 ? aHk : bHk;
      a3 = fminf(t2 ? aH2 : aH, t2 ? bH : bH2);
    }
    skf[tid] = e1;
    mk2f[tid] = e2v;
    if (a2 - a1 <= EPSM) {
      if (a3 - a1 > EPSM) { int p = atomicAdd(cntB, 1); pairL[p] = tid; }
      else                { int p = atomicAdd(cntC, 1); fullL[p] = tid; }
    }
  }
  __syncthreads();

  int nB = *cntB, nC = *cntC;

  // ---- case B: exact pairwise compare {k1,k2}, one thread per token ----
  if (tid < nB) {
    int t = pairL[tid];
    int ka = skf[t], kb = mk2f[t];
    const float* za = z_e + (size_t)b * CHW + s0 + t;
    const float* ea = emb + ((size_t)ka << 6);
    const float* ebp = emb + ((size_t)kb << 6);
    float zz = 0.f, da = 0.f, db = 0.f;
    #pragma unroll
    for (int c = 0; c < 64; ++c) {
      float zv = za[(size_t)c * HW] * sRstd[c];
      zz = fmaf(zv, zv, zz);
      da = fmaf(ea[c], zv, da);
      db = fmaf(ebp[c], zv, db);
    }
    float d1 = (zz - 2.0f * da) + eeg[ka];
    float d2 = (zz - 2.0f * db) + eeg[kb];
    if (d2 < d1 || (d2 == d1 && kb < ka)) skf[t] = kb;
  }
  __syncthreads();

  // ---- case C (rare): block-cooperative full scan, exact formula ----
  for (int i = 0; i < nC; ++i) {
    int t = fullL[i];
    if (tid < 64) zf[tid] = z_e[(size_t)b * CHW + (size_t)tid * HW + s0 + t] * sRstd[tid];
    __syncthreads();
    const float4* zf4 = (const float4*)zf;
    const float* er0 = emb + ((size_t)(tid << 2) << 6);
    float zz = 0.f;
    float dot[4] = {0.f, 0.f, 0.f, 0.f};
    #pragma unroll
    for (int c4 = 0; c4 < 16; ++c4) {
      float4 zv = zf4[c4];
      zz = fmaf(zv.x, zv.x, zz); zz = fmaf(zv.y, zv.y, zz);
      zz = fmaf(zv.z, zv.z, zz); zz = fmaf(zv.w, zv.w, zz);
      #pragma unroll
      for (int j = 0; j < 4; ++j) {
        float4 ev = *(const float4*)(er0 + (j << 6) + (c4 << 2));
        dot[j] = fmaf(ev.x, zv.x, dot[j]);
        dot[j] = fmaf(ev.y, zv.y, dot[j]);
        dot[j] = fmaf(ev.z, zv.z, dot[j]);
        dot[j] = fmaf(ev.w, zv.w, dot[j]);
      }
    }
    float bdl = FLT_MAX; int bkl = 0;
    #pragma unroll
    for (int j = 0; j < 4; ++j) {
      float dd = (zz - 2.0f * dot[j]) + eeg[(tid << 2) + j];
      if (dd < bdl) { bdl = dd; bkl = (tid << 2) + j; }
    }
    #pragma unroll
    for (int m = 1; m <= 32; m <<= 1) {
      float od = __shfl_xor(bdl, m, 64);
      int   ok = __shfl_xor(bkl, m, 64);
      if (od < bdl || (od == bdl && ok < bkl)) { bdl = od; bkl = ok; }
    }
    if (lane == 0) { fbd4[wv] = bdl; fbk4[wv] = bkl; }
    __syncthreads();
    if (tid == 0) {
      float bb2 = fbd4[0]; int kk2 = fbk4[0];
      #pragma unroll
      for (int w = 1; w < 4; ++w)
        if (fbd4[w] < bb2 || (fbd4[w] == bb2 && fbk4[w] < kk2)) { bb2 = fbd4[w]; kk2 = fbk4[w]; }
      skf[t] = kk2;
    }
    __syncthreads();
  }
  __syncthreads();

  if (tid < 64) {
    int k = skf[tid];
    out_idx[(blk << 6) + tid] = (float)k;
    atomicAdd(&hist[k], 1);      // distributed histogram (no serial tail re-read)
  }

  // ---- epilogue: z recomputed bit-consistently from global, coalesced stores ----
  {
    int t = tid & 63;
    int g = tid >> 6;
    int kq = skf[t];
    const float* eq = emb + ((size_t)kq << 6) + (g << 4);
    const float* zb2 = z_e + (size_t)b * CHW + (size_t)(g << 4) * HW + s0 + t;
    float* ob = out_zq + (size_t)b * CHW + (size_t)(g << 4) * HW + s0 + t;
    float lsum = 0.f;
    #pragma unroll
    for (int j4 = 0; j4 < 4; ++j4) {
      float4 ev = *(const float4*)(eq + (j4 << 2));
      #pragma unroll
      for (int u = 0; u < 4; ++u) {
        int jj = (j4 << 2) + u;
        float zv = zb2[(size_t)jj * HW] * sRstd[(g << 4) + jj];
        float e = (&ev.x)[u];
        float df = zv - e;
        lsum = fmaf(df, df, lsum);
        ob[(size_t)jj * HW] = zv + (e - zv);
      }
    }
    for (int o = 32; o > 0; o >>= 1) lsum += __shfl_down(lsum, o, 64);
    if (lane == 0) sred[wv] = lsum;
  }
  __syncthreads();

  // ---- fused finalize via done-counter (validated pattern); tail is tiny ----
  if (tid == 0) {
    loss_part[blk] = sred[0] + sred[1] + sred[2] + sred[3];
    __threadfence();
    int prev = atomicAdd(done, 1);
    lastFlag = (prev == 1023);
  }
  __syncthreads();
  if (!lastFlag) return;

  double ls = (double)loss_part[tid] + (double)loss_part[tid + 256]
            + (double)loss_part[tid + 512] + (double)loss_part[tid + 768];
  double hsum = 0.0;
  #pragma unroll
  for (int jj = 0; jj < 4; ++jj) {
    float p = (float)hist[tid + (jj << 8)] * (1.0f / 65536.0f);
    float lg = logf(fmaxf(p, 1e-10f));
    hsum += (double)(p * lg);
  }
  for (int o = 32; o > 0; o >>= 1) {
    ls += __shfl_down(ls, o, 64);
    hsum += __shfl_down(hsum, o, 64);
  }
  if (lane == 0) { rl[wv] = ls; rh[wv] = hsum; }
  __syncthreads();
  if (tid == 0) {
    double L = rl[0] + rl[1] + rl[2] + rl[3];
    double Hn = rh[0] + rh[1] + rh[2] + rh[3];
    float m = (float)(L / (double)NELEM);
    out_scalars[0] = 0.25f * m + m;
    out_scalars[1] = expf((float)(-Hn));
  }
}

extern "C" void kernel_launch(void* const* d_in, const int* in_sizes, int n_in,
                              void* d_out, int out_size, void* d_ws, size_t ws_size,
                              hipStream_t stream) {
  const float* z_e = (const float*)d_in[0];
  const float* emb = (const float*)d_in[1];
  float* ws = (float*)d_ws;
  float* loss_part = ws + WS_LOSS;
  double* part = (double*)(ws + WS_PART);
  float* eeg = ws + WS_EE;
  unsigned short* e2g = (unsigned short*)(ws + WS_E2);
  int* hist = (int*)(ws + WS_HIST);
  int* done = (int*)(ws + WS_DONE);     // ws use ~279 KB

  float* out = (float*)d_out;
  float* out_zq = out;                  // 4194304
  float* out_scalars = out + NELEM;     // vq_loss, perplexity
  float* out_idx = out + NELEM + 2;     // 65536 indices as float

  k_pre<<<272, 1024, 0, stream>>>(z_e, emb, part, e2g, eeg, hist, done);
  k_vq<<<1024, 256, 0, stream>>>(z_e, emb, part, eeg, e2g, out_zq, out_idx,
                                 loss_part, done, out_scalars, hist);
}